// Round 10
// baseline (832.679 us; speedup 1.0000x reference)
//
#include <hip/hip_runtime.h>
#include <math.h>

#define PI_D 3.14159265358979323846

// ---------------- dims ----------------
#define BATCH   1024
#define TLEN    16000
#define NFFT    400
#define HOP     200
#define NFRAME  81          // 1 + (16400-400)/200
#define NBIN    201
#define NMEL    128
#define HID     128
#define TSTEPS  79          // after conv k=3 valid
#define GATES   512         // 4*HID

#define KDFT    416         // 400 padded to 32
#define NDFT    512         // cos 0..200, sin 256..456, rest zero
#define SINOFF  256
#define KPOW    224         // 201 padded to 32
#define KCONV   384
#define NCHUNK  2
#define CHROWS  (BATCH*NFRAME/NCHUNK)   // 41472 = 648*64

static inline size_t al512(size_t v){ return (v + 511) & ~((size_t)511); }

// ---------------- bf16 split helpers ----------------
__device__ __forceinline__ unsigned short bf_rne(float f){
    unsigned u = __float_as_uint(f);
    u += 0x7FFF + ((u >> 16) & 1);
    return (unsigned short)(u >> 16);
}
__device__ __forceinline__ void bf_split(float f, unsigned short& h, unsigned short& l){
    h = bf_rne(f);
    float hf = __uint_as_float(((unsigned)h) << 16);
    l = bf_rne(f - hf);
}
// Fast truncation split (GEMM staging hot path): h=trunc(f), l=trunc(f-h).
__device__ __forceinline__ void bf_split_fast(float f, unsigned short& h, unsigned short& l){
    unsigned u = __float_as_uint(f);
    h = (unsigned short)(u >> 16);
    float hf = __uint_as_float(u & 0xFFFF0000u);
    l = (unsigned short)(__float_as_uint(f - hf) >> 16);
}

// B-table k-index swizzle: within each 32-k block, 16B chunk q of column n is
// stored at chunk position q ^ ((n>>1)&3). This is the exact LDS image the
// GEMM's linear global_load_lds deposit needs for conflict-free swizzled reads.
__device__ __forceinline__ int kswz(int n, int k){
    return (k & ~31) | (((((k >> 3) & 3) ^ ((n >> 1) & 3))) << 3) | (k & 7);
}

typedef short bf16x8 __attribute__((ext_vector_type(8)));
typedef float f32x4  __attribute__((ext_vector_type(4)));
typedef unsigned short us8 __attribute__((ext_vector_type(8)));
typedef unsigned short us4 __attribute__((ext_vector_type(4)));
typedef _Float16 f16x8 __attribute__((ext_vector_type(8)));

// async global->LDS, 16B per lane, dest = wave-uniform base + lane*16
__device__ __forceinline__ void gld16(const unsigned short* g, unsigned short* l){
    __builtin_amdgcn_global_load_lds(
        (const __attribute__((address_space(1))) unsigned int*)g,
        (__attribute__((address_space(3))) unsigned int*)l, 16, 0, 0);
}

// barrier_lds: LDS-only fence barrier; global loads/stores ride across
// (used in lstm_k so the X-prefetch loads and H-stores are not drained).
__device__ __forceinline__ void barrier_lds(){
    __builtin_amdgcn_sched_barrier(0);
    asm volatile("s_waitcnt lgkmcnt(0)" ::: "memory");
    __builtin_amdgcn_s_barrier();
    __builtin_amdgcn_sched_barrier(0);
}

// ---------------- setup kernels: B matrices pre-transposed + pre-split ----------------
__global__ void setup_dft_t(unsigned short* __restrict__ th, unsigned short* __restrict__ tl){
    int idx = blockIdx.x*256 + threadIdx.x;
    if (idx >= NDFT*KDFT) return;
    int n = idx / KDFT, k = idx % KDFT;
    double v = 0.0;
    if (k < 400) {
        double w = 0.5 - 0.5*cos(2.0*PI_D*(double)k/400.0);
        if (n < NBIN)                              v = w * cos(2.0*PI_D*(double)((k*n)%400)/400.0);
        else if (n >= SINOFF && n < SINOFF + NBIN) v = w * sin(2.0*PI_D*(double)((k*(n-SINOFF))%400)/400.0);
    }
    unsigned short h, l; bf_split((float)v, h, l);
    int o = n*KDFT + kswz(n, k);
    th[o] = h; tl[o] = l;
}

__global__ void setup_fb_t(unsigned short* __restrict__ fh, unsigned short* __restrict__ fl){
    int idx = blockIdx.x*256 + threadIdx.x;
    if (idx >= NMEL*KPOW) return;
    int m = idx / KPOW, f = idx % KPOW;
    float v = 0.f;
    if (f < NBIN) {
        double melmax = 2595.0 * log10(1.0 + 8000.0/700.0);
        double p0 = 700.0*(pow(10.0, melmax*(double)(m  )/129.0/2595.0) - 1.0);
        double p1 = 700.0*(pow(10.0, melmax*(double)(m+1)/129.0/2595.0) - 1.0);
        double p2 = 700.0*(pow(10.0, melmax*(double)(m+2)/129.0/2595.0) - 1.0);
        double freq = 40.0 * (double)f;
        double dn = (freq - p0)/(p1 - p0);
        double up = (p2 - freq)/(p2 - p1);
        double t  = dn < up ? dn : up;
        if (t < 0.0) t = 0.0;
        v = (float)t;
    }
    unsigned short h, l; bf_split(v, h, l);
    int o = m*KPOW + kswz(m, f);
    fh[o] = h; fl[o] = l;
}

__global__ void setup_wc_t(unsigned short* __restrict__ wh, unsigned short* __restrict__ wl,
                           const float* __restrict__ cw){
    int idx = blockIdx.x*256 + threadIdx.x;
    if (idx >= NMEL*KCONV) return;
    int o = idx / KCONV, kk = idx % KCONV;
    int ksh = kk >> 7, i = kk & 127;
    unsigned short h, l; bf_split(cw[o*384 + i*3 + ksh], h, l);
    int p = o*KCONV + kswz(o, kk);
    wh[p] = h; wl[p] = l;
}

// W tables for the X-GEMMs, GATE-INTERLEAVED columns: table row c' = j*4+g
// holds orig column c = g*128+j. This makes the 4 gate addends of hidden j
// adjacent in X -> lstm_k reads them as one float4, and the U-frag mapping
// below puts gi,gf,gg,go of one (row,j) into ONE LANE's accumulators.
__global__ void setup_w_t(unsigned short* __restrict__ wh, unsigned short* __restrict__ wl,
                          const float* __restrict__ w){
    int idx = blockIdx.x*256 + threadIdx.x;
    if (idx >= GATES*HID) return;
    int cp = idx / HID, i = idx % HID;
    int c = (cp & 3)*128 + (cp >> 2);      // orig gate-major column
    unsigned short h, l; bf_split(w[(size_t)i*GATES + c], h, l);
    int p = cp*HID + kswz(cp, i);
    wh[p] = h; wl[p] = l;
}

// permuted biases for the X-GEMMs
__global__ void setup_pb(float* __restrict__ pb1, float* __restrict__ pb2,
                         const float* __restrict__ b1, const float* __restrict__ b2){
    int cp = blockIdx.x*256 + threadIdx.x;
    if (cp >= GATES) return;
    int c = (cp & 3)*128 + (cp >> 2);
    pb1[cp] = b1[c];
    pb2[cp] = b2[c];
}

__global__ void setup_comb(float* __restrict__ cwm, float* __restrict__ cb,
                           const float* __restrict__ fc1w, const float* __restrict__ fc1b,
                           const float* __restrict__ projw, const float* __restrict__ projb){
    int idx = blockIdx.x*256 + threadIdx.x;
    if (idx < 128*64) {
        int i = idx / 64, o = idx % 64;
        float v = 0.f;
        if (o < 35) {
            double s = 0.0;
            for (int m = 0; m < 128; m++) s += (double)fc1w[i*128+m] * (double)projw[m*35+o];
            v = (float)s;
        }
        cwm[idx] = v;
    } else if (idx < 128*64 + 64) {
        int o = idx - 128*64;
        float v = 0.f;
        if (o < 35) {
            double s = (double)projb[o];
            for (int m = 0; m < 128; m++) s += (double)fc1b[m] * (double)projw[m*35+o];
            v = (float)s;
        }
        cb[o] = v;
    }
}

// U (HID x GATES row-major) -> fp16 MFMA B-fragments, gate-interleaved:
// frag f = w*8+nt covers gate g=f&3, hidden block jg=f>>2 (cols j=jg*16+l15).
// So lane's acc[jgl*4+g] = gate g of j = (2w+jgl)*16+l15 -> gates lane-local.
__global__ void setup_uf(_Float16* __restrict__ uf, const float* __restrict__ u){
    int idx = blockIdx.x*256 + threadIdx.x;
    if (idx >= 65536) return;
    int jj   = idx & 7;
    int lane = (idx >> 3) & 63;
    int nt   = (idx >> 9) & 7;
    int ks   = (idx >> 12) & 3;
    int w    = (idx >> 14) & 3;
    int f = w*8 + nt;
    int g = f & 3;
    int jcol = (f >> 2)*16 + (lane & 15);
    int k = ks*32 + (lane >> 4)*8 + jj;
    uf[idx] = (_Float16)u[(size_t)k*GATES + g*128 + jcol];
}

// ---------------- MFMA split-bf16 GEMM ----------------
// Depth-2 software pipeline, single __syncthreads per K-step (R8 lesson:
// counted-vmcnt raw barriers are NULL-to-negative on this 2-phase structure;
// R7 form is the measured best).
//   WIDE=false: 128x128, 2x2 waves (N=128 ops: power, conv)
//   WIDE=true:   64x256, 1x4 waves (N=512 ops: DFT, X-gemms)
enum AMode { A_NORMAL=0, A_FRAMES=1, A_POWER=2, A_CONV3=3 };

template<int AMODE, bool BIAS, int NT, bool WIDE>
__global__ __launch_bounds__(256)
void mgemm_k(const float* __restrict__ A,
             const unsigned short* __restrict__ BTh, const unsigned short* __restrict__ BTl,
             const float* __restrict__ bias, float* __restrict__ C,
             int Ksteps, int lda, int kstride, int ldc,
             const float* __restrict__ aux, int rowbase)
{
    constexpr int BM = WIDE ? 64 : 128;
    constexpr int BN = WIDE ? 256 : 128;
    constexpr int AP = BM / 32;          // A staging passes (32 rows each)
    __shared__ unsigned short Ash[2][BM][32], Asl[2][BM][32];
    __shared__ unsigned short Bsh[2][BN][32], Bsl[2][BN][32];

    // bijective XCD-chunk swizzle (m204), n-tile fastest
    const int nwg = gridDim.x;
    const int qq = nwg >> 3, rmd = nwg & 7;
    const int xcd = blockIdx.x & 7, loc = blockIdx.x >> 3;
    const int swz = (xcd < rmd ? xcd*(qq+1) : rmd*(qq+1) + (xcd - rmd)*qq) + loc;
    constexpr int LGNT = (NT == 4) ? 2 : (NT == 2) ? 1 : 0;
    const int m0 = (swz >> LGNT) * BM;
    const int n0 = (swz & (NT-1)) * BN;

    const int tid = threadIdx.x;
    const int lane = tid & 63, w = tid >> 6;
    const int wr = WIDE ? 0 : (w >> 1) * 64;        // wave's 64x64 sub-tile
    const int wc = WIDE ? w * 64 : (w & 1) * 64;
    const int l15 = lane & 15;
    // swizzled chunk position for fragment reads: q ^ ((row>>1)&3)
    const int swf = ((lane & 15) >> 1) & 3;
    const int pos = (((lane >> 4) ^ swf) << 3);     // short index, 16B aligned

    // A staging: 8 threads/row, AP passes of 32 rows; thread covers 4 k-values
    const int sr  = tid >> 3;                       // row within pass
    const int wcol = (((((tid & 7) >> 1)) ^ ((tid >> 4) & 3)) << 3) + ((tid & 1) << 2);

    float va0[AP*4], vb0[AP*4], va1[AP*4], vb1[AP*4];

    auto issue_loads = [&](float (&va)[AP*4], float (&vb)[AP*4], int ksn){
        const int k0n = ksn * 32;
        #pragma unroll
        for (int p = 0; p < AP; p++) {
            const int row = p*32 + sr;
            const int kk = k0n + (tid & 7)*4;
            if constexpr (AMODE == A_NORMAL) {
                *(float4*)&va[p*4] = *(const float4*)(A + (size_t)(m0+row)*lda + kk);
            } else if constexpr (AMODE == A_POWER) {
                const float* src = A + (size_t)(m0+row)*lda + kk;
                *(float4*)&va[p*4] = *(const float4*)(src);
                *(float4*)&vb[p*4] = *(const float4*)(src + SINOFF);
            } else if constexpr (AMODE == A_FRAMES) {
                const int rr = rowbase + m0 + row;
                const int b = rr / NFRAME, f = rr - b*NFRAME;
                const float* xb = aux + (size_t)b * TLEN;
                const int q0 = f*HOP + kk - 200;
                if (q0 >= 0 && q0 + 3 < TLEN) {
                    *(float4*)&va[p*4] = *(const float4*)(xb + q0);
                } else {
                    #pragma unroll
                    for (int j = 0; j < 4; j++) {
                        int q = q0 + j;
                        if (q < 0) q = -q;
                        else if (q >= TLEN) q = 2*TLEN - 2 - q;
                        va[p*4+j] = xb[q];
                    }
                }
            } else { // A_CONV3
                const int rr = m0 + row;
                const int b = rr / TSTEPS, t = rr - b*TSTEPS;
                const int ksh = kk >> 7, i = kk & 127;
                *(float4*)&va[p*4] = *(const float4*)(aux + ((size_t)(b*NFRAME + t + ksh)*NMEL + i));
            }
        }
        (void)vb;
    };
    auto write_stage = [&](float (&va)[AP*4], float (&vb)[AP*4], int wb){
        #pragma unroll
        for (int p = 0; p < AP; p++) {
            const int row = p*32 + sr;
            us4 hv, lv;
            #pragma unroll
            for (int j = 0; j < 4; j++) {
                float f = va[p*4+j];
                if constexpr (AMODE == A_POWER) f = f*f + vb[p*4+j]*vb[p*4+j];
                unsigned short h, l; bf_split_fast(f, h, l);
                hv[j] = h; lv[j] = l;
            }
            *(us4*)&Ash[wb][row][wcol] = hv;
            *(us4*)&Asl[wb][row][wcol] = lv;
        }
        (void)vb;
    };
    auto dma_b = [&](int wb, int ksn){
        const int k0n = ksn * 32;
        if constexpr (WIDE) {
            #pragma unroll
            for (int p = 0; p < 4; p++) {
                const int row = w*64 + p*16;
                const size_t o = (size_t)(n0 + row + (lane >> 2))*kstride + k0n + (lane & 3)*8;
                gld16(BTh + o, &Bsh[wb][row][0]);
                gld16(BTl + o, &Bsl[wb][row][0]);
            }
        } else {
            #pragma unroll
            for (int p = 0; p < 2; p++) {
                const int row = p*64 + w*16;
                const size_t o = (size_t)(n0 + row + (lane >> 2))*kstride + k0n + (lane & 3)*8;
                gld16(BTh + o, &Bsh[wb][row][0]);
                gld16(BTl + o, &Bsl[wb][row][0]);
            }
        }
    };

    f32x4 acc[4][4] = {};

    // prologue: stage ks=0 into buf0 (via set1 as temp), preload ks=1 into set0
    issue_loads(va1, vb1, 0);
    dma_b(0, 0);
    write_stage(va1, vb1, 0);
    issue_loads(va0, vb0, 1);
    __syncthreads();

    // iter body: cur regs hold data(ks+1); oth regs get data(ks+2); buf = ks&1
    auto iter = [&](int ks, float (&vac)[AP*4], float (&vbc)[AP*4],
                    float (&vao)[AP*4], float (&vbo)[AP*4], int bufc){
        const bool pf1 = (ks + 1 < Ksteps);
        const bool pf2 = (ks + 2 < Ksteps);
        if (pf2) issue_loads(vao, vbo, ks + 2);
        if (pf1) dma_b(bufc ^ 1, ks + 1);

        bf16x8 ah[4], al[4];
        #pragma unroll
        for (int mt = 0; mt < 4; mt++) {
            ah[mt] = *(const bf16x8*)&Ash[bufc][wr + mt*16 + l15][pos];
            al[mt] = *(const bf16x8*)&Asl[bufc][wr + mt*16 + l15][pos];
        }
        #pragma unroll
        for (int nt = 0; nt < 4; nt++) {
            const int nr = wc + nt*16 + l15;
            bf16x8 bh = *(const bf16x8*)&Bsh[bufc][nr][pos];
            bf16x8 bl = *(const bf16x8*)&Bsl[bufc][nr][pos];
            #pragma unroll
            for (int mt = 0; mt < 4; mt++) {
                acc[mt][nt] = __builtin_amdgcn_mfma_f32_16x16x32_bf16(ah[mt], bh, acc[mt][nt], 0, 0, 0);
                acc[mt][nt] = __builtin_amdgcn_mfma_f32_16x16x32_bf16(ah[mt], bl, acc[mt][nt], 0, 0, 0);
                acc[mt][nt] = __builtin_amdgcn_mfma_f32_16x16x32_bf16(al[mt], bh, acc[mt][nt], 0, 0, 0);
            }
        }

        if (pf1) {
            write_stage(vac, vbc, bufc ^ 1);   // data(ks+1), loaded a full iter ago
            __syncthreads();
        }
    };

    for (int ks = 0; ks < Ksteps; ks += 2) {
        iter(ks, va0, vb0, va1, vb1, 0);
        if (ks + 1 < Ksteps) iter(ks + 1, va1, vb1, va0, vb0, 1);
    }

    const int quad = lane >> 4;
    #pragma unroll
    for (int nt = 0; nt < 4; nt++) {
        const int col = n0 + wc + (nt << 4) + l15;
        float b = 0.f;
        if constexpr (BIAS) b = bias[col];
        #pragma unroll
        for (int mt = 0; mt < 4; mt++) {
            #pragma unroll
            for (int r = 0; r < 4; r++) {
                const int row = m0 + wr + (mt << 4) + quad*4 + r;
                C[(size_t)row*ldc + col] = acc[mt][nt][r] + b;
            }
        }
    }
}

// ---------------- small fp32 GEMM (final 1024x35 only) ----------------
__global__ __launch_bounds__(256)
void gemm_small(const float* __restrict__ A, const float* __restrict__ Bm,
                const float* __restrict__ bias, float* __restrict__ C,
                int M, int N, int K, int lda, int ldb, int ldc)
{
    __shared__ float As[16][64+4];
    __shared__ float Bs[16][64];
    const int tid = threadIdx.x;
    const int tx = tid & 15, ty = tid >> 4;
    const int m0 = blockIdx.x * 64;
    float acc[4][4] = {{0,0,0,0},{0,0,0,0},{0,0,0,0},{0,0,0,0}};
    const int am = tid >> 2, ak = (tid & 3) * 4;
    const int bk = tid >> 4, bn = (tid & 15) * 4;
    for (int k0 = 0; k0 < K; k0 += 16) {
        float4 av = *(const float4*)(A + (size_t)(m0+am)*lda + k0 + ak);
        As[ak+0][am]=av.x; As[ak+1][am]=av.y; As[ak+2][am]=av.z; As[ak+3][am]=av.w;
        *(float4*)&Bs[bk][bn] = *(const float4*)(Bm + (size_t)(k0+bk)*ldb + bn);
        __syncthreads();
        #pragma unroll
        for (int k = 0; k < 16; k++) {
            float4 a = *(const float4*)&As[k][ty*4];
            float4 b = *(const float4*)&Bs[k][tx*4];
            #pragma unroll
            for (int i = 0; i < 4; i++) {
                float av_ = ((const float*)&a)[i];
                acc[i][0] = fmaf(av_, b.x, acc[i][0]);
                acc[i][1] = fmaf(av_, b.y, acc[i][1]);
                acc[i][2] = fmaf(av_, b.z, acc[i][2]);
                acc[i][3] = fmaf(av_, b.w, acc[i][3]);
            }
        }
        __syncthreads();
    }
    #pragma unroll
    for (int ir = 0; ir < 4; ir++) {
        const int row = m0 + ty*4 + ir;
        #pragma unroll
        for (int jc = 0; jc < 4; jc++) {
            const int col = tx*4 + jc;
            if (col < N) C[(size_t)row*ldc + col] = acc[ir][jc] + bias[col];
        }
    }
}

// ---------------- LSTM recurrence: gates LANE-LOCAL, 1 barrier/step ----------------
// R10: gate-interleaved U columns put gi,gf,gg,go of one (row,j) into one
// lane's acc[jgl*4+0..3][rr] -> entire cell update in registers (no gs LDS
// round-trip, c-state register-resident). LROWS=16 uses the full M=16 MFMA
// tile (no wasted rows, all 64 lanes active in gate VALU). hsA double-buffered
// -> exactly ONE LDS-only barrier per step; X prefetch + H stores ride across.
__device__ __forceinline__ float sigm_f(float x){ return 1.f/(1.f + __expf(-x)); }
__device__ __forceinline__ float tanh_f(float x){ float e = __expf(2.f*x); return 1.f - 2.f/(e + 1.f); }

#define LROWS 16
#define LTHREADS 256
#define HPAD 136

__global__ __launch_bounds__(LTHREADS, 1)
void lstm_k(const float* __restrict__ X, const _Float16* __restrict__ Uf, float* __restrict__ H)
{
    __shared__ _Float16 hsA[2][16*HPAD];
    const int tid = threadIdx.x;
    const int b0 = blockIdx.x * LROWS;
    const int lane = tid & 63, w = tid >> 6;      // wave 0..3
    const int l15 = lane & 15, quad = lane >> 4;
    const int jc0 = 32*w + l15;                   // j for jgl=0 (jgl=1: +16)

    // Pinned U fragments (32 frags = 128 VGPRs). Volatile-asm pin: remat
    // cannot clone past it (R4/R5 lesson: else re-loaded from L2 every step).
    f32x4 bfr[4][8];
    #pragma unroll
    for (int ks = 0; ks < 4; ks++)
        #pragma unroll
        for (int nt = 0; nt < 8; nt++) {
            bfr[ks][nt] = *(const f32x4*)(Uf + ((((w*4 + ks)*8 + nt)*64 + lane) << 3));
            asm volatile("" : "+v"(bfr[ks][nt]));
        }

    {   // zero-init both h buffers
        _Float16* hz = &hsA[0][0];
        for (int i = tid; i < 2*16*HPAD; i += LTHREADS) hz[i] = (_Float16)0.f;
    }

    float cst[8] = {0,0,0,0,0,0,0,0};             // c-state: [rr][jgl]
    const float* xp[4];                            // per-row X base (at col j*4)
    float* hp[4];
    #pragma unroll
    for (int rr = 0; rr < 4; rr++) {
        const int br = b0 + quad*4 + rr;
        xp[rr] = X + (size_t)br*TSTEPS*GATES + jc0*4;
        hp[rr] = H + (size_t)br*TSTEPS*HID;
    }
    __syncthreads();

    // X prefetch for t=0 (4 gate addends of one j = one float4)
    float4 xv[8];                                  // [rr*2+jgl]
    #pragma unroll
    for (int rr = 0; rr < 4; rr++)
        #pragma unroll
        for (int jgl = 0; jgl < 2; jgl++)
            xv[rr*2+jgl] = *(const float4*)(xp[rr] + jgl*64);

    for (int t = 0; t < TSTEPS; t++) {
        const int p = t & 1;

        f16x8 ah[4];
        #pragma unroll
        for (int ks = 0; ks < 4; ks++)
            ah[ks] = *(const f16x8*)&hsA[p][l15*HPAD + ks*32 + quad*8];

        f32x4 acc[8] = {};
        #pragma unroll
        for (int ks = 0; ks < 4; ks++)
            #pragma unroll
            for (int nt = 0; nt < 8; nt++)
                acc[nt] = __builtin_amdgcn_mfma_f32_16x16x32_f16(
                    ah[ks], __builtin_bit_cast(f16x8, bfr[ks][nt]), acc[nt], 0, 0, 0);

        // cell update fully in-register; write h to other buffer + H (global)
        #pragma unroll
        for (int jgl = 0; jgl < 2; jgl++) {
            #pragma unroll
            for (int rr = 0; rr < 4; rr++) {
                const float4 xg = xv[rr*2+jgl];
                const float gi = acc[jgl*4+0][rr] + xg.x;
                const float gf = acc[jgl*4+1][rr] + xg.y;
                const float gg = acc[jgl*4+2][rr] + xg.z;
                const float go = acc[jgl*4+3][rr] + xg.w;
                const float cn = sigm_f(gf)*cst[rr*2+jgl] + sigm_f(gi)*tanh_f(gg);
                cst[rr*2+jgl] = cn;
                const float hn = sigm_f(go)*tanh_f(cn);
                hp[rr][(size_t)t*HID + jc0 + jgl*16] = hn;       // rides across barrier
                hsA[p^1][(quad*4+rr)*HPAD + jc0 + jgl*16] = (_Float16)hn;
            }
        }

        // prefetch X for t+1 (consumed after next barrier+MFMA: full cover)
        if (t + 1 < TSTEPS) {
            #pragma unroll
            for (int rr = 0; rr < 4; rr++)
                #pragma unroll
                for (int jgl = 0; jgl < 2; jgl++)
                    xv[rr*2+jgl] = *(const float4*)(xp[rr] + (size_t)(t+1)*GATES + jgl*64);
        }

        barrier_lds();   // single barrier/step: makes hsA[p^1] visible
    }
}

// ---------------- mean over time ----------------
__global__ void mean_k(const float* __restrict__ H, float* __restrict__ Mh){
    const int idx = blockIdx.x*256 + threadIdx.x;
    if (idx >= BATCH*HID) return;
    const int b = idx >> 7, j = idx & 127;
    const float* p = H + (size_t)b*TSTEPS*HID + j;
    float s = 0.f;
    for (int t = 0; t < TSTEPS; t++) s += p[(size_t)t*HID];
    Mh[idx] = s * (1.0f/(float)TSTEPS);
}

// ---------------- launcher ----------------
extern "C" void kernel_launch(void* const* d_in, const int* in_sizes, int n_in,
                              void* d_out, int out_size, void* d_ws, size_t ws_size,
                              hipStream_t stream)
{
    const float* x      = (const float*)d_in[0];
    const float* conv_w = (const float*)d_in[1];
    const float* conv_b = (const float*)d_in[2];
    const float* W1     = (const float*)d_in[3];
    const float* U1     = (const float*)d_in[4];
    const float* b1     = (const float*)d_in[5];
    const float* W2     = (const float*)d_in[6];
    const float* U2     = (const float*)d_in[7];
    const float* b2     = (const float*)d_in[8];
    const float* fc1_w  = (const float*)d_in[9];
    const float* fc1_b  = (const float*)d_in[10];
    const float* proj_w = (const float*)d_in[11];
    const float* proj_b = (const float*)d_in[12];
    float* out = (float*)d_out;

    // ---- workspace layout (~241 MiB < 256 MiB) ----
    char* ws = (char*)d_ws;
    size_t off = 0;
    unsigned short* Tth = (unsigned short*)(ws + off); off = al512(off + (size_t)NDFT*KDFT*2);
    unsigned short* Ttl = (unsigned short*)(ws + off); off = al512(off + (size_t)NDFT*KDFT*2);
    unsigned short* fbh = (unsigned short*)(ws + off); off = al512(off + (size_t)NMEL*KPOW*2);
    unsigned short* fbl = (unsigned short*)(ws + off); off = al512(off + (size_t)NMEL*KPOW*2);
    unsigned short* wch = (unsigned short*)(ws + off); off = al512(off + (size_t)NMEL*KCONV*2);
    unsigned short* wcl = (unsigned short*)(ws + off); off = al512(off + (size_t)NMEL*KCONV*2);
    unsigned short* w1h = (unsigned short*)(ws + off); off = al512(off + (size_t)GATES*HID*2);
    unsigned short* w1l = (unsigned short*)(ws + off); off = al512(off + (size_t)GATES*HID*2);
    unsigned short* w2h = (unsigned short*)(ws + off); off = al512(off + (size_t)GATES*HID*2);
    unsigned short* w2l = (unsigned short*)(ws + off); off = al512(off + (size_t)GATES*HID*2);
    float* Cw   = (float*)(ws + off); off = al512(off + (size_t)128*64*4);
    float* Cb   = (float*)(ws + off); off = al512(off + (size_t)64*4);
    float* Pb1  = (float*)(ws + off); off = al512(off + (size_t)GATES*4);
    float* Pb2  = (float*)(ws + off); off = al512(off + (size_t)GATES*4);
    float* Mh   = (float*)(ws + off); off = al512(off + (size_t)BATCH*HID*4);
    _Float16* Uf1 = (_Float16*)(ws + off); off = al512(off + (size_t)65536*2);
    _Float16* Uf2 = (_Float16*)(ws + off); off = al512(off + (size_t)65536*2);
    float* MEL  = (float*)(ws + off); off = al512(off + (size_t)BATCH*NFRAME*NMEL*4);   // 42.5 MB
    float* CONV = (float*)(ws + off); off = al512(off + (size_t)BATCH*TSTEPS*NMEL*4);   // 41.4 MB
    float* X    = (float*)(ws + off); off = al512(off + (size_t)BATCH*TSTEPS*GATES*4);  // 165.7 MB
    float* DFT = X;     // DFT chunk scratch (CHROWS*512*4 = 84.9 MB) dead before X written
    float* H1  = MEL;   // MEL dead after CONV computed
    float* H2  = CONV;  // CONV dead after X1 computed
    (void)ws_size; (void)out_size; (void)n_in; (void)in_sizes;

    // setup tables
    setup_dft_t<<<(NDFT*KDFT + 255)/256, 256, 0, stream>>>(Tth, Ttl);
    setup_fb_t <<<(NMEL*KPOW + 255)/256, 256, 0, stream>>>(fbh, fbl);
    setup_wc_t <<<(NMEL*KCONV + 255)/256, 256, 0, stream>>>(wch, wcl, conv_w);
    setup_w_t  <<<(GATES*HID + 255)/256, 256, 0, stream>>>(w1h, w1l, W1);
    setup_w_t  <<<(GATES*HID + 255)/256, 256, 0, stream>>>(w2h, w2l, W2);
    setup_pb   <<<(GATES + 255)/256, 256, 0, stream>>>(Pb1, Pb2, b1, b2);
    setup_comb <<<(128*64 + 64 + 255)/256, 256, 0, stream>>>(Cw, Cb, fc1_w, fc1_b, proj_w, proj_b);
    setup_uf   <<<65536/256, 256, 0, stream>>>(Uf1, U1);
    setup_uf   <<<65536/256, 256, 0, stream>>>(Uf2, U2);

    // mel spectrogram in chunks: frames @ DFT -> power @ fb
    for (int ch = 0; ch < NCHUNK; ch++) {
        const int rowbase = ch * CHROWS;
        mgemm_k<A_FRAMES,false,2,true><<<(CHROWS/64)*2, 256, 0, stream>>>(
            nullptr, Tth, Ttl, nullptr, DFT, KDFT/32, 0, KDFT, NDFT, x, rowbase);
        mgemm_k<A_POWER,false,1,false><<<CHROWS/128, 256, 0, stream>>>(
            DFT, fbh, fbl, nullptr, MEL + (size_t)rowbase*NMEL, KPOW/32, NDFT, KPOW, NMEL, nullptr, 0);
    }

    // conv1d (k=3, valid) as im2col GEMM, bias fused
    mgemm_k<A_CONV3,true,1,false><<<BATCH*TSTEPS/128, 256, 0, stream>>>(
        nullptr, wch, wcl, conv_b, CONV, KCONV/32, 0, KCONV, NMEL, MEL, 0);

    // layer 1: X1 = CONV @ W1 + b1 (gate-interleaved cols) ; recurrence
    mgemm_k<A_NORMAL,true,2,true><<<(BATCH*TSTEPS/64)*2, 256, 0, stream>>>(
        CONV, w1h, w1l, Pb1, X, HID/32, NMEL, HID, GATES, nullptr, 0);
    lstm_k<<<BATCH/LROWS, LTHREADS, 0, stream>>>(X, Uf1, H1);

    // layer 2
    mgemm_k<A_NORMAL,true,2,true><<<(BATCH*TSTEPS/64)*2, 256, 0, stream>>>(
        H1, w2h, w2l, Pb2, X, HID/32, HID, HID, GATES, nullptr, 0);
    lstm_k<<<BATCH/LROWS, LTHREADS, 0, stream>>>(X, Uf2, H2);

    // mean over time, then folded fc1+proj
    mean_k<<<(BATCH*HID + 255)/256, 256, 0, stream>>>(H2, Mh);
    gemm_small<<<BATCH/64, 256, 0, stream>>>(Mh, Cw, Cb, out, BATCH, 35, HID, HID, 64, 35);
}

// Round 11
// 671.254 us; speedup vs baseline: 1.2405x; 1.2405x over previous
//
#include <hip/hip_runtime.h>
#include <math.h>

#define PI_D 3.14159265358979323846

// ---------------- dims ----------------
#define BATCH   1024
#define TLEN    16000
#define NFFT    400
#define HOP     200
#define NFRAME  81          // 1 + (16400-400)/200
#define NBIN    201
#define NMEL    128
#define HID     128
#define TSTEPS  79          // after conv k=3 valid
#define GATES   512         // 4*HID

#define KDFT    416         // 400 padded to 32
#define NDFT    512         // cos 0..200, sin 256..456, rest zero
#define SINOFF  256
#define KPOW    224         // 201 padded to 32
#define KCONV   384
#define NCHUNK  2
#define CHROWS  (BATCH*NFRAME/NCHUNK)   // 41472 = 648*64

static inline size_t al512(size_t v){ return (v + 511) & ~((size_t)511); }

// ---------------- bf16 split helpers ----------------
__device__ __forceinline__ unsigned short bf_rne(float f){
    unsigned u = __float_as_uint(f);
    u += 0x7FFF + ((u >> 16) & 1);
    return (unsigned short)(u >> 16);
}
__device__ __forceinline__ void bf_split(float f, unsigned short& h, unsigned short& l){
    h = bf_rne(f);
    float hf = __uint_as_float(((unsigned)h) << 16);
    l = bf_rne(f - hf);
}
// Fast truncation split (GEMM staging hot path): h=trunc(f), l=trunc(f-h).
__device__ __forceinline__ void bf_split_fast(float f, unsigned short& h, unsigned short& l){
    unsigned u = __float_as_uint(f);
    h = (unsigned short)(u >> 16);
    float hf = __uint_as_float(u & 0xFFFF0000u);
    l = (unsigned short)(__float_as_uint(f - hf) >> 16);
}

// B-table k-index swizzle: within each 32-k block, 16B chunk q of column n is
// stored at chunk position q ^ ((n>>1)&3). This is the exact LDS image the
// GEMM's linear global_load_lds deposit needs for conflict-free swizzled reads.
__device__ __forceinline__ int kswz(int n, int k){
    return (k & ~31) | (((((k >> 3) & 3) ^ ((n >> 1) & 3))) << 3) | (k & 7);
}

typedef short bf16x8 __attribute__((ext_vector_type(8)));
typedef float f32x4  __attribute__((ext_vector_type(4)));
typedef unsigned short us8 __attribute__((ext_vector_type(8)));
typedef unsigned short us4 __attribute__((ext_vector_type(4)));
typedef _Float16 f16x8 __attribute__((ext_vector_type(8)));

// async global->LDS, 16B per lane, dest = wave-uniform base + lane*16
__device__ __forceinline__ void gld16(const unsigned short* g, unsigned short* l){
    __builtin_amdgcn_global_load_lds(
        (const __attribute__((address_space(1))) unsigned int*)g,
        (__attribute__((address_space(3))) unsigned int*)l, 16, 0, 0);
}

// barrier_lds: LDS-only fence barrier; global loads/stores ride across
// (used in lstm_k so the X-prefetch loads and H-stores are not drained).
__device__ __forceinline__ void barrier_lds(){
    __builtin_amdgcn_sched_barrier(0);
    asm volatile("s_waitcnt lgkmcnt(0)" ::: "memory");
    __builtin_amdgcn_s_barrier();
    __builtin_amdgcn_sched_barrier(0);
}

// ---------------- setup kernels: B matrices pre-transposed + pre-split ----------------
__global__ void setup_dft_t(unsigned short* __restrict__ th, unsigned short* __restrict__ tl){
    int idx = blockIdx.x*256 + threadIdx.x;
    if (idx >= NDFT*KDFT) return;
    int n = idx / KDFT, k = idx % KDFT;
    double v = 0.0;
    if (k < 400) {
        double w = 0.5 - 0.5*cos(2.0*PI_D*(double)k/400.0);
        if (n < NBIN)                              v = w * cos(2.0*PI_D*(double)((k*n)%400)/400.0);
        else if (n >= SINOFF && n < SINOFF + NBIN) v = w * sin(2.0*PI_D*(double)((k*(n-SINOFF))%400)/400.0);
    }
    unsigned short h, l; bf_split((float)v, h, l);
    int o = n*KDFT + kswz(n, k);
    th[o] = h; tl[o] = l;
}

__global__ void setup_fb_t(unsigned short* __restrict__ fh, unsigned short* __restrict__ fl){
    int idx = blockIdx.x*256 + threadIdx.x;
    if (idx >= NMEL*KPOW) return;
    int m = idx / KPOW, f = idx % KPOW;
    float v = 0.f;
    if (f < NBIN) {
        double melmax = 2595.0 * log10(1.0 + 8000.0/700.0);
        double p0 = 700.0*(pow(10.0, melmax*(double)(m  )/129.0/2595.0) - 1.0);
        double p1 = 700.0*(pow(10.0, melmax*(double)(m+1)/129.0/2595.0) - 1.0);
        double p2 = 700.0*(pow(10.0, melmax*(double)(m+2)/129.0/2595.0) - 1.0);
        double freq = 40.0 * (double)f;
        double dn = (freq - p0)/(p1 - p0);
        double up = (p2 - freq)/(p2 - p1);
        double t  = dn < up ? dn : up;
        if (t < 0.0) t = 0.0;
        v = (float)t;
    }
    unsigned short h, l; bf_split(v, h, l);
    int o = m*KPOW + kswz(m, f);
    fh[o] = h; fl[o] = l;
}

__global__ void setup_wc_t(unsigned short* __restrict__ wh, unsigned short* __restrict__ wl,
                           const float* __restrict__ cw){
    int idx = blockIdx.x*256 + threadIdx.x;
    if (idx >= NMEL*KCONV) return;
    int o = idx / KCONV, kk = idx % KCONV;
    int ksh = kk >> 7, i = kk & 127;
    unsigned short h, l; bf_split(cw[o*384 + i*3 + ksh], h, l);
    int p = o*KCONV + kswz(o, kk);
    wh[p] = h; wl[p] = l;
}

__global__ void setup_w_t(unsigned short* __restrict__ wh, unsigned short* __restrict__ wl,
                          const float* __restrict__ w){
    int idx = blockIdx.x*256 + threadIdx.x;
    if (idx >= GATES*HID) return;
    int c = idx / HID, i = idx % HID;
    unsigned short h, l; bf_split(w[(size_t)i*GATES + c], h, l);
    int p = c*HID + kswz(c, i);
    wh[p] = h; wl[p] = l;
}

__global__ void setup_comb(float* __restrict__ cwm, float* __restrict__ cb,
                           const float* __restrict__ fc1w, const float* __restrict__ fc1b,
                           const float* __restrict__ projw, const float* __restrict__ projb){
    int idx = blockIdx.x*256 + threadIdx.x;
    if (idx < 128*64) {
        int i = idx / 64, o = idx % 64;
        float v = 0.f;
        if (o < 35) {
            double s = 0.0;
            for (int m = 0; m < 128; m++) s += (double)fc1w[i*128+m] * (double)projw[m*35+o];
            v = (float)s;
        }
        cwm[idx] = v;
    } else if (idx < 128*64 + 64) {
        int o = idx - 128*64;
        float v = 0.f;
        if (o < 35) {
            double s = (double)projb[o];
            for (int m = 0; m < 128; m++) s += (double)fc1b[m] * (double)projw[m*35+o];
            v = (float)s;
        }
        cb[o] = v;
    }
}

// U (HID x GATES row-major) -> fp16 in MFMA B-fragment order (8-wave lstm).
__global__ void setup_uf(_Float16* __restrict__ uf, const float* __restrict__ u){
    int idx = blockIdx.x*256 + threadIdx.x;
    if (idx >= 65536) return;
    int j    = idx & 7;
    int lane = (idx >> 3) & 63;
    int nt   = (idx >> 9) & 3;
    int ks   = (idx >> 11) & 3;
    int w    = (idx >> 13) & 7;
    int k = ks*32 + (lane >> 4)*8 + j;
    int c = w*64 + nt*16 + (lane & 15);
    uf[idx] = (_Float16)u[(size_t)k*GATES + c];
}

// ---------------- MFMA split-bf16 GEMM ----------------
// Depth-2 software pipeline, single __syncthreads per K-step (R8 lesson:
// counted-vmcnt raw barriers are NULL-to-negative on this 2-phase structure;
// R7 form is the measured best).
//   WIDE=false: 128x128, 2x2 waves (N=128 ops: power, conv)
//   WIDE=true:   64x256, 1x4 waves (N=512 ops: DFT, X-gemms)
enum AMode { A_NORMAL=0, A_FRAMES=1, A_POWER=2, A_CONV3=3 };

template<int AMODE, bool BIAS, int NT, bool WIDE>
__global__ __launch_bounds__(256)
void mgemm_k(const float* __restrict__ A,
             const unsigned short* __restrict__ BTh, const unsigned short* __restrict__ BTl,
             const float* __restrict__ bias, float* __restrict__ C,
             int Ksteps, int lda, int kstride, int ldc,
             const float* __restrict__ aux, int rowbase)
{
    constexpr int BM = WIDE ? 64 : 128;
    constexpr int BN = WIDE ? 256 : 128;
    constexpr int AP = BM / 32;          // A staging passes (32 rows each)
    __shared__ unsigned short Ash[2][BM][32], Asl[2][BM][32];
    __shared__ unsigned short Bsh[2][BN][32], Bsl[2][BN][32];

    // bijective XCD-chunk swizzle (m204), n-tile fastest
    const int nwg = gridDim.x;
    const int qq = nwg >> 3, rmd = nwg & 7;
    const int xcd = blockIdx.x & 7, loc = blockIdx.x >> 3;
    const int swz = (xcd < rmd ? xcd*(qq+1) : rmd*(qq+1) + (xcd - rmd)*qq) + loc;
    constexpr int LGNT = (NT == 4) ? 2 : (NT == 2) ? 1 : 0;
    const int m0 = (swz >> LGNT) * BM;
    const int n0 = (swz & (NT-1)) * BN;

    const int tid = threadIdx.x;
    const int lane = tid & 63, w = tid >> 6;
    const int wr = WIDE ? 0 : (w >> 1) * 64;        // wave's 64x64 sub-tile
    const int wc = WIDE ? w * 64 : (w & 1) * 64;
    const int l15 = lane & 15;
    // swizzled chunk position for fragment reads: q ^ ((row>>1)&3)
    const int swf = ((lane & 15) >> 1) & 3;
    const int pos = (((lane >> 4) ^ swf) << 3);     // short index, 16B aligned

    // A staging: 8 threads/row, AP passes of 32 rows; thread covers 4 k-values
    const int sr  = tid >> 3;                       // row within pass
    const int wcol = (((((tid & 7) >> 1)) ^ ((tid >> 4) & 3)) << 3) + ((tid & 1) << 2);

    float va0[AP*4], vb0[AP*4], va1[AP*4], vb1[AP*4];

    auto issue_loads = [&](float (&va)[AP*4], float (&vb)[AP*4], int ksn){
        const int k0n = ksn * 32;
        #pragma unroll
        for (int p = 0; p < AP; p++) {
            const int row = p*32 + sr;
            const int kk = k0n + (tid & 7)*4;
            if constexpr (AMODE == A_NORMAL) {
                *(float4*)&va[p*4] = *(const float4*)(A + (size_t)(m0+row)*lda + kk);
            } else if constexpr (AMODE == A_POWER) {
                const float* src = A + (size_t)(m0+row)*lda + kk;
                *(float4*)&va[p*4] = *(const float4*)(src);
                *(float4*)&vb[p*4] = *(const float4*)(src + SINOFF);
            } else if constexpr (AMODE == A_FRAMES) {
                const int rr = rowbase + m0 + row;
                const int b = rr / NFRAME, f = rr - b*NFRAME;
                const float* xb = aux + (size_t)b * TLEN;
                const int q0 = f*HOP + kk - 200;
                if (q0 >= 0 && q0 + 3 < TLEN) {
                    *(float4*)&va[p*4] = *(const float4*)(xb + q0);
                } else {
                    #pragma unroll
                    for (int j = 0; j < 4; j++) {
                        int q = q0 + j;
                        if (q < 0) q = -q;
                        else if (q >= TLEN) q = 2*TLEN - 2 - q;
                        va[p*4+j] = xb[q];
                    }
                }
            } else { // A_CONV3
                const int rr = m0 + row;
                const int b = rr / TSTEPS, t = rr - b*TSTEPS;
                const int ksh = kk >> 7, i = kk & 127;
                *(float4*)&va[p*4] = *(const float4*)(aux + ((size_t)(b*NFRAME + t + ksh)*NMEL + i));
            }
        }
        (void)vb;
    };
    auto write_stage = [&](float (&va)[AP*4], float (&vb)[AP*4], int wb){
        #pragma unroll
        for (int p = 0; p < AP; p++) {
            const int row = p*32 + sr;
            us4 hv, lv;
            #pragma unroll
            for (int j = 0; j < 4; j++) {
                float f = va[p*4+j];
                if constexpr (AMODE == A_POWER) f = f*f + vb[p*4+j]*vb[p*4+j];
                unsigned short h, l; bf_split_fast(f, h, l);
                hv[j] = h; lv[j] = l;
            }
            *(us4*)&Ash[wb][row][wcol] = hv;
            *(us4*)&Asl[wb][row][wcol] = lv;
        }
        (void)vb;
    };
    auto dma_b = [&](int wb, int ksn){
        const int k0n = ksn * 32;
        if constexpr (WIDE) {
            #pragma unroll
            for (int p = 0; p < 4; p++) {
                const int row = w*64 + p*16;
                const size_t o = (size_t)(n0 + row + (lane >> 2))*kstride + k0n + (lane & 3)*8;
                gld16(BTh + o, &Bsh[wb][row][0]);
                gld16(BTl + o, &Bsl[wb][row][0]);
            }
        } else {
            #pragma unroll
            for (int p = 0; p < 2; p++) {
                const int row = p*64 + w*16;
                const size_t o = (size_t)(n0 + row + (lane >> 2))*kstride + k0n + (lane & 3)*8;
                gld16(BTh + o, &Bsh[wb][row][0]);
                gld16(BTl + o, &Bsl[wb][row][0]);
            }
        }
    };

    f32x4 acc[4][4] = {};

    // prologue: stage ks=0 into buf0 (via set1 as temp), preload ks=1 into set0
    issue_loads(va1, vb1, 0);
    dma_b(0, 0);
    write_stage(va1, vb1, 0);
    issue_loads(va0, vb0, 1);
    __syncthreads();

    // iter body: cur regs hold data(ks+1); oth regs get data(ks+2); buf = ks&1
    auto iter = [&](int ks, float (&vac)[AP*4], float (&vbc)[AP*4],
                    float (&vao)[AP*4], float (&vbo)[AP*4], int bufc){
        const bool pf1 = (ks + 1 < Ksteps);
        const bool pf2 = (ks + 2 < Ksteps);
        if (pf2) issue_loads(vao, vbo, ks + 2);
        if (pf1) dma_b(bufc ^ 1, ks + 1);

        bf16x8 ah[4], al[4];
        #pragma unroll
        for (int mt = 0; mt < 4; mt++) {
            ah[mt] = *(const bf16x8*)&Ash[bufc][wr + mt*16 + l15][pos];
            al[mt] = *(const bf16x8*)&Asl[bufc][wr + mt*16 + l15][pos];
        }
        #pragma unroll
        for (int nt = 0; nt < 4; nt++) {
            const int nr = wc + nt*16 + l15;
            bf16x8 bh = *(const bf16x8*)&Bsh[bufc][nr][pos];
            bf16x8 bl = *(const bf16x8*)&Bsl[bufc][nr][pos];
            #pragma unroll
            for (int mt = 0; mt < 4; mt++) {
                acc[mt][nt] = __builtin_amdgcn_mfma_f32_16x16x32_bf16(ah[mt], bh, acc[mt][nt], 0, 0, 0);
                acc[mt][nt] = __builtin_amdgcn_mfma_f32_16x16x32_bf16(ah[mt], bl, acc[mt][nt], 0, 0, 0);
                acc[mt][nt] = __builtin_amdgcn_mfma_f32_16x16x32_bf16(al[mt], bh, acc[mt][nt], 0, 0, 0);
            }
        }

        if (pf1) {
            write_stage(vac, vbc, bufc ^ 1);   // data(ks+1), loaded a full iter ago
            __syncthreads();
        }
    };

    for (int ks = 0; ks < Ksteps; ks += 2) {
        iter(ks, va0, vb0, va1, vb1, 0);
        if (ks + 1 < Ksteps) iter(ks + 1, va1, vb1, va0, vb0, 1);
    }

    const int quad = lane >> 4;
    #pragma unroll
    for (int nt = 0; nt < 4; nt++) {
        const int col = n0 + wc + (nt << 4) + l15;
        float b = 0.f;
        if constexpr (BIAS) b = bias[col];
        #pragma unroll
        for (int mt = 0; mt < 4; mt++) {
            #pragma unroll
            for (int r = 0; r < 4; r++) {
                const int row = m0 + wr + (mt << 4) + quad*4 + r;
                C[(size_t)row*ldc + col] = acc[mt][nt][r] + b;
            }
        }
    }
}

// ---------------- small fp32 GEMM (final 1024x35 only) ----------------
__global__ __launch_bounds__(256)
void gemm_small(const float* __restrict__ A, const float* __restrict__ Bm,
                const float* __restrict__ bias, float* __restrict__ C,
                int M, int N, int K, int lda, int ldb, int ldc)
{
    __shared__ float As[16][64+4];
    __shared__ float Bs[16][64];
    const int tid = threadIdx.x;
    const int tx = tid & 15, ty = tid >> 4;
    const int m0 = blockIdx.x * 64;
    float acc[4][4] = {{0,0,0,0},{0,0,0,0},{0,0,0,0},{0,0,0,0}};
    const int am = tid >> 2, ak = (tid & 3) * 4;
    const int bk = tid >> 4, bn = (tid & 15) * 4;
    for (int k0 = 0; k0 < K; k0 += 16) {
        float4 av = *(const float4*)(A + (size_t)(m0+am)*lda + k0 + ak);
        As[ak+0][am]=av.x; As[ak+1][am]=av.y; As[ak+2][am]=av.z; As[ak+3][am]=av.w;
        *(float4*)&Bs[bk][bn] = *(const float4*)(Bm + (size_t)(k0+bk)*ldb + bn);
        __syncthreads();
        #pragma unroll
        for (int k = 0; k < 16; k++) {
            float4 a = *(const float4*)&As[k][ty*4];
            float4 b = *(const float4*)&Bs[k][tx*4];
            #pragma unroll
            for (int i = 0; i < 4; i++) {
                float av_ = ((const float*)&a)[i];
                acc[i][0] = fmaf(av_, b.x, acc[i][0]);
                acc[i][1] = fmaf(av_, b.y, acc[i][1]);
                acc[i][2] = fmaf(av_, b.z, acc[i][2]);
                acc[i][3] = fmaf(av_, b.w, acc[i][3]);
            }
        }
        __syncthreads();
    }
    #pragma unroll
    for (int ir = 0; ir < 4; ir++) {
        const int row = m0 + ty*4 + ir;
        #pragma unroll
        for (int jc = 0; jc < 4; jc++) {
            const int col = tx*4 + jc;
            if (col < N) C[(size_t)row*ldc + col] = acc[ir][jc] + bias[col];
        }
    }
}

// ---------------- LSTM recurrence: MFMA, U register-resident ----------------
// R11: back to the full-occupancy R7 shape (256 blocks x 512 thr = one cell
// per thread in the gate phase) + two surgical fixes:
//  (1) hsA rows replicated x4 (rows r,r+4,r+8,r+12 identical) -> every quad's
//      acc holds bit-identical gate values -> ALL 64 lanes write gs (4 stores
//      each, static-index cndmask select) instead of quad0's 16 serialized.
//  (2) depth-2 X prefetch: loads for t+2 issued at t (~2 steps of latency
//      cover vs ~0.5 at depth-1). barrier_lds keeps them in flight.
__device__ __forceinline__ float sigm_f(float x){ return 1.f/(1.f + __expf(-x)); }
__device__ __forceinline__ float tanh_f(float x){ float e = __expf(2.f*x); return 1.f - 2.f/(e + 1.f); }

#define LROWS 4
#define LTHREADS 512
#define HPAD 136

__global__ __launch_bounds__(LTHREADS, 2)
void lstm_k(const float* __restrict__ X, const _Float16* __restrict__ Uf, float* __restrict__ H)
{
    __shared__ _Float16 hsA[16*HPAD];
    __shared__ float gs[GATES*5];
    const int tid = threadIdx.x;
    const int b0 = blockIdx.x * LROWS;
    const int lane = tid & 63, w = tid >> 6;
    const int m16 = lane & 15, quad = lane >> 4;
    const int r = tid >> 7;
    const int j = tid & 127;

    // Preload B fragments, pin in VGPRs (R4/R5 lesson: else re-loaded from
    // L2 every step -> L2-bound).
    f32x4 bfr[4][4];
    #pragma unroll
    for (int ks = 0; ks < 4; ks++)
        #pragma unroll
        for (int nt = 0; nt < 4; nt++) {
            bfr[ks][nt] = *(const f32x4*)(Uf + ((((w*4 + ks)*4 + nt)*64 + lane) << 3));
            asm volatile("" : "+v"(bfr[ks][nt]));
        }

    for (int i = tid; i < 16*HPAD; i += LTHREADS) hsA[i] = (_Float16)0.f;
    float cst = 0.f;
    const float* xb = X + ((size_t)(b0 + r)*TSTEPS)*GATES + j;
    __syncthreads();

    // depth-2 X prefetch: x (for t), x1 (for t+1); load t+2 inside the loop
    float xi  = xb[0],     xf  = xb[128],     xg  = xb[256],     xo  = xb[384];
    float xi1 = xb[GATES], xf1 = xb[GATES+128], xg1 = xb[GATES+256], xo1 = xb[GATES+384];

    for (int t = 0; t < TSTEPS; t++) {
        float xi2 = 0.f, xf2 = 0.f, xg2 = 0.f, xo2 = 0.f;
        if (t + 2 < TSTEPS) {
            const float* xp = xb + (size_t)(t + 2)*GATES;
            xi2 = xp[0]; xf2 = xp[128]; xg2 = xp[256]; xo2 = xp[384];
        }

        f16x8 ah[4];
        #pragma unroll
        for (int ks = 0; ks < 4; ks++)
            ah[ks] = *(const f16x8*)&hsA[m16*HPAD + ks*32 + quad*8];

        f32x4 acc[4] = {{0,0,0,0},{0,0,0,0},{0,0,0,0},{0,0,0,0}};
        #pragma unroll
        for (int ks = 0; ks < 4; ks++)
            #pragma unroll
            for (int nt = 0; nt < 4; nt++)
                acc[nt] = __builtin_amdgcn_mfma_f32_16x16x32_f16(
                    ah[ks], __builtin_bit_cast(f16x8, bfr[ks][nt]), acc[nt], 0, 0, 0);

        // all-lane gs write: quad q writes nt=q (acc rows are x4-replicated ->
        // acc[q][rr] == gate(row rr, col w*64+q*16+m16) in every quad).
        {
            const f32x4 s0 = (quad & 1) ? acc[1] : acc[0];
            const f32x4 s1 = (quad & 1) ? acc[3] : acc[2];
            const f32x4 av = (quad & 2) ? s1 : s0;
            const int c = w*64 + quad*16 + m16;
            gs[c*5 + 0] = av[0];
            gs[c*5 + 1] = av[1];
            gs[c*5 + 2] = av[2];
            gs[c*5 + 3] = av[3];
        }
        barrier_lds();

        {
            const float gi = gs[(      j)*5 + r] + xi;
            const float gf = gs[(128 + j)*5 + r] + xf;
            const float gg = gs[(256 + j)*5 + r] + xg;
            const float go = gs[(384 + j)*5 + r] + xo;
            const float cn = sigm_f(gf)*cst + sigm_f(gi)*tanh_f(gg);
            cst = cn;
            const float hn = sigm_f(go)*tanh_f(cn);
            H[((size_t)(b0 + r)*TSTEPS + t)*HID + j] = hn;   // rides across barriers
            const _Float16 hh = (_Float16)hn;
            hsA[(r     )*HPAD + j] = hh;                     // x4 row replication
            hsA[(r +  4)*HPAD + j] = hh;
            hsA[(r +  8)*HPAD + j] = hh;
            hsA[(r + 12)*HPAD + j] = hh;
        }
        barrier_lds();

        xi = xi1; xf = xf1; xg = xg1; xo = xo1;
        xi1 = xi2; xf1 = xf2; xg1 = xg2; xo1 = xo2;
    }
}

// ---------------- mean over time ----------------
__global__ void mean_k(const float* __restrict__ H, float* __restrict__ Mh){
    const int idx = blockIdx.x*256 + threadIdx.x;
    if (idx >= BATCH*HID) return;
    const int b = idx >> 7, j = idx & 127;
    const float* p = H + (size_t)b*TSTEPS*HID + j;
    float s = 0.f;
    for (int t = 0; t < TSTEPS; t++) s += p[(size_t)t*HID];
    Mh[idx] = s * (1.0f/(float)TSTEPS);
}

// ---------------- launcher ----------------
extern "C" void kernel_launch(void* const* d_in, const int* in_sizes, int n_in,
                              void* d_out, int out_size, void* d_ws, size_t ws_size,
                              hipStream_t stream)
{
    const float* x      = (const float*)d_in[0];
    const float* conv_w = (const float*)d_in[1];
    const float* conv_b = (const float*)d_in[2];
    const float* W1     = (const float*)d_in[3];
    const float* U1     = (const float*)d_in[4];
    const float* b1     = (const float*)d_in[5];
    const float* W2     = (const float*)d_in[6];
    const float* U2     = (const float*)d_in[7];
    const float* b2     = (const float*)d_in[8];
    const float* fc1_w  = (const float*)d_in[9];
    const float* fc1_b  = (const float*)d_in[10];
    const float* proj_w = (const float*)d_in[11];
    const float* proj_b = (const float*)d_in[12];
    float* out = (float*)d_out;

    // ---- workspace layout (~241 MiB < 256 MiB) ----
    char* ws = (char*)d_ws;
    size_t off = 0;
    unsigned short* Tth = (unsigned short*)(ws + off); off = al512(off + (size_t)NDFT*KDFT*2);
    unsigned short* Ttl = (unsigned short*)(ws + off); off = al512(off + (size_t)NDFT*KDFT*2);
    unsigned short* fbh = (unsigned short*)(ws + off); off = al512(off + (size_t)NMEL*KPOW*2);
    unsigned short* fbl = (unsigned short*)(ws + off); off = al512(off + (size_t)NMEL*KPOW*2);
    unsigned short* wch = (unsigned short*)(ws + off); off = al512(off + (size_t)NMEL*KCONV*2);
    unsigned short* wcl = (unsigned short*)(ws + off); off = al512(off + (size_t)NMEL*KCONV*2);
    unsigned short* w1h = (unsigned short*)(ws + off); off = al512(off + (size_t)GATES*HID*2);
    unsigned short* w1l = (unsigned short*)(ws + off); off = al512(off + (size_t)GATES*HID*2);
    unsigned short* w2h = (unsigned short*)(ws + off); off = al512(off + (size_t)GATES*HID*2);
    unsigned short* w2l = (unsigned short*)(ws + off); off = al512(off + (size_t)GATES*HID*2);
    float* Cw   = (float*)(ws + off); off = al512(off + (size_t)128*64*4);
    float* Cb   = (float*)(ws + off); off = al512(off + (size_t)64*4);
    float* Mh   = (float*)(ws + off); off = al512(off + (size_t)BATCH*HID*4);
    _Float16* Uf1 = (_Float16*)(ws + off); off = al512(off + (size_t)65536*2);
    _Float16* Uf2 = (_Float16*)(ws + off); off = al512(off + (size_t)65536*2);
    float* MEL  = (float*)(ws + off); off = al512(off + (size_t)BATCH*NFRAME*NMEL*4);   // 42.5 MB
    float* CONV = (float*)(ws + off); off = al512(off + (size_t)BATCH*TSTEPS*NMEL*4);   // 41.4 MB
    float* X    = (float*)(ws + off); off = al512(off + (size_t)BATCH*TSTEPS*GATES*4);  // 165.7 MB
    float* DFT = X;     // DFT chunk scratch (CHROWS*512*4 = 84.9 MB) dead before X written
    float* H1  = MEL;   // MEL dead after CONV computed
    float* H2  = CONV;  // CONV dead after X1 computed
    (void)ws_size; (void)out_size; (void)n_in; (void)in_sizes;

    // setup tables
    setup_dft_t<<<(NDFT*KDFT + 255)/256, 256, 0, stream>>>(Tth, Ttl);
    setup_fb_t <<<(NMEL*KPOW + 255)/256, 256, 0, stream>>>(fbh, fbl);
    setup_wc_t <<<(NMEL*KCONV + 255)/256, 256, 0, stream>>>(wch, wcl, conv_w);
    setup_w_t  <<<(GATES*HID + 255)/256, 256, 0, stream>>>(w1h, w1l, W1);
    setup_w_t  <<<(GATES*HID + 255)/256, 256, 0, stream>>>(w2h, w2l, W2);
    setup_comb <<<(128*64 + 64 + 255)/256, 256, 0, stream>>>(Cw, Cb, fc1_w, fc1_b, proj_w, proj_b);
    setup_uf   <<<65536/256, 256, 0, stream>>>(Uf1, U1);
    setup_uf   <<<65536/256, 256, 0, stream>>>(Uf2, U2);

    // mel spectrogram in chunks: frames @ DFT -> power @ fb
    for (int ch = 0; ch < NCHUNK; ch++) {
        const int rowbase = ch * CHROWS;
        mgemm_k<A_FRAMES,false,2,true><<<(CHROWS/64)*2, 256, 0, stream>>>(
            nullptr, Tth, Ttl, nullptr, DFT, KDFT/32, 0, KDFT, NDFT, x, rowbase);
        mgemm_k<A_POWER,false,1,false><<<CHROWS/128, 256, 0, stream>>>(
            DFT, fbh, fbl, nullptr, MEL + (size_t)rowbase*NMEL, KPOW/32, NDFT, KPOW, NMEL, nullptr, 0);
    }

    // conv1d (k=3, valid) as im2col GEMM, bias fused
    mgemm_k<A_CONV3,true,1,false><<<BATCH*TSTEPS/128, 256, 0, stream>>>(
        nullptr, wch, wcl, conv_b, CONV, KCONV/32, 0, KCONV, NMEL, MEL, 0);

    // layer 1: X1 = CONV @ W1 + b1 ; recurrence
    mgemm_k<A_NORMAL,true,2,true><<<(BATCH*TSTEPS/64)*2, 256, 0, stream>>>(
        CONV, w1h, w1l, b1, X, HID/32, NMEL, HID, GATES, nullptr, 0);
    lstm_k<<<BATCH/LROWS, LTHREADS, 0, stream>>>(X, Uf1, H1);

    // layer 2
    mgemm_k<A_NORMAL,true,2,true><<<(BATCH*TSTEPS/64)*2, 256, 0, stream>>>(
        H1, w2h, w2l, b2, X, HID/32, HID, HID, GATES, nullptr, 0);
    lstm_k<<<BATCH/LROWS, LTHREADS, 0, stream>>>(X, Uf2, H2);

    // mean over time, then folded fc1+proj
    mean_k<<<(BATCH*HID + 255)/256, 256, 0, stream>>>(H2, Mh);
    gemm_small<<<BATCH/64, 256, 0, stream>>>(Mh, Cw, Cb, out, BATCH, 35, HID, HID, 64, 35);
}

// Round 12
// 642.532 us; speedup vs baseline: 1.2959x; 1.0447x over previous
//
#include <hip/hip_runtime.h>
#include <math.h>

#define PI_D 3.14159265358979323846

// ---------------- dims ----------------
#define BATCH   1024
#define TLEN    16000
#define NFFT    400
#define HOP     200
#define NFRAME  81          // 1 + (16400-400)/200
#define NBIN    201
#define NMEL    128
#define HID     128
#define TSTEPS  79          // after conv k=3 valid
#define GATES   512         // 4*HID
#define TOTROWS (BATCH*NFRAME)   // 82944 = 1296*64 = 648*128

#define KDFT    416         // 400 padded to 32
#define NDFT    512         // BIN-INTERLEAVED: col 2n = cos_n, col 2n+1 = sin_n (n=0..200), rest 0
#define KPOW    224         // 201 bins padded to 32
#define LPOW    224         // POW row stride (floats)
#define KCONV   384

static inline size_t al512(size_t v){ return (v + 511) & ~((size_t)511); }

// ---------------- bf16 split helpers ----------------
__device__ __forceinline__ unsigned short bf_rne(float f){
    unsigned u = __float_as_uint(f);
    u += 0x7FFF + ((u >> 16) & 1);
    return (unsigned short)(u >> 16);
}
__device__ __forceinline__ void bf_split(float f, unsigned short& h, unsigned short& l){
    h = bf_rne(f);
    float hf = __uint_as_float(((unsigned)h) << 16);
    l = bf_rne(f - hf);
}
// Fast truncation split (GEMM staging hot path): h=trunc(f), l=trunc(f-h).
__device__ __forceinline__ void bf_split_fast(float f, unsigned short& h, unsigned short& l){
    unsigned u = __float_as_uint(f);
    h = (unsigned short)(u >> 16);
    float hf = __uint_as_float(u & 0xFFFF0000u);
    l = (unsigned short)(__float_as_uint(f - hf) >> 16);
}

// B-table k-index swizzle: within each 32-k block, 16B chunk q of column n is
// stored at chunk position q ^ ((n>>1)&3). This is the exact LDS image the
// GEMM's linear global_load_lds deposit needs for conflict-free swizzled reads.
__device__ __forceinline__ int kswz(int n, int k){
    return (k & ~31) | (((((k >> 3) & 3) ^ ((n >> 1) & 3))) << 3) | (k & 7);
}

typedef short bf16x8 __attribute__((ext_vector_type(8)));
typedef float f32x4  __attribute__((ext_vector_type(4)));
typedef unsigned short us8 __attribute__((ext_vector_type(8)));
typedef unsigned short us4 __attribute__((ext_vector_type(4)));
typedef _Float16 f16x8 __attribute__((ext_vector_type(8)));

// async global->LDS, 16B per lane, dest = wave-uniform base + lane*16
__device__ __forceinline__ void gld16(const unsigned short* g, unsigned short* l){
    __builtin_amdgcn_global_load_lds(
        (const __attribute__((address_space(1))) unsigned int*)g,
        (__attribute__((address_space(3))) unsigned int*)l, 16, 0, 0);
}

// barrier_lds: LDS-only fence barrier; global loads/stores ride across
// (used in lstm_k so the X-prefetch loads and H-stores are not drained).
__device__ __forceinline__ void barrier_lds(){
    __builtin_amdgcn_sched_barrier(0);
    asm volatile("s_waitcnt lgkmcnt(0)" ::: "memory");
    __builtin_amdgcn_s_barrier();
    __builtin_amdgcn_sched_barrier(0);
}

// ---------------- setup kernels: B matrices pre-transposed + pre-split ----------------
// DFT table, BIN-INTERLEAVED columns: col 2n = windowed cos_n, col 2n+1 =
// windowed sin_n. Same values as before, pure column permutation -> the DFT
// epilogue finds re/im of one bin in adjacent lanes (shfl_xor(1)) and can
// emit power directly, eliminating the separate POWER kernel's re-read.
__global__ void setup_dft_t(unsigned short* __restrict__ th, unsigned short* __restrict__ tl){
    int idx = blockIdx.x*256 + threadIdx.x;
    if (idx >= NDFT*KDFT) return;
    int n = idx / KDFT, k = idx % KDFT;
    double v = 0.0;
    if (k < 400 && n < 402) {
        double w = 0.5 - 0.5*cos(2.0*PI_D*(double)k/400.0);
        int bin = n >> 1;
        if ((n & 1) == 0) v = w * cos(2.0*PI_D*(double)((k*bin)%400)/400.0);
        else              v = w * sin(2.0*PI_D*(double)((k*bin)%400)/400.0);
    }
    unsigned short h, l; bf_split((float)v, h, l);
    int o = n*KDFT + kswz(n, k);
    th[o] = h; tl[o] = l;
}

__global__ void setup_fb_t(unsigned short* __restrict__ fh, unsigned short* __restrict__ fl){
    int idx = blockIdx.x*256 + threadIdx.x;
    if (idx >= NMEL*KPOW) return;
    int m = idx / KPOW, f = idx % KPOW;
    float v = 0.f;
    if (f < NBIN) {
        double melmax = 2595.0 * log10(1.0 + 8000.0/700.0);
        double p0 = 700.0*(pow(10.0, melmax*(double)(m  )/129.0/2595.0) - 1.0);
        double p1 = 700.0*(pow(10.0, melmax*(double)(m+1)/129.0/2595.0) - 1.0);
        double p2 = 700.0*(pow(10.0, melmax*(double)(m+2)/129.0/2595.0) - 1.0);
        double freq = 40.0 * (double)f;
        double dn = (freq - p0)/(p1 - p0);
        double up = (p2 - freq)/(p2 - p1);
        double t  = dn < up ? dn : up;
        if (t < 0.0) t = 0.0;
        v = (float)t;
    }
    unsigned short h, l; bf_split(v, h, l);
    int o = m*KPOW + kswz(m, f);
    fh[o] = h; fl[o] = l;
}

__global__ void setup_wc_t(unsigned short* __restrict__ wh, unsigned short* __restrict__ wl,
                           const float* __restrict__ cw){
    int idx = blockIdx.x*256 + threadIdx.x;
    if (idx >= NMEL*KCONV) return;
    int o = idx / KCONV, kk = idx % KCONV;
    int ksh = kk >> 7, i = kk & 127;
    unsigned short h, l; bf_split(cw[o*384 + i*3 + ksh], h, l);
    int p = o*KCONV + kswz(o, kk);
    wh[p] = h; wl[p] = l;
}

__global__ void setup_w_t(unsigned short* __restrict__ wh, unsigned short* __restrict__ wl,
                          const float* __restrict__ w){
    int idx = blockIdx.x*256 + threadIdx.x;
    if (idx >= GATES*HID) return;
    int c = idx / HID, i = idx % HID;
    unsigned short h, l; bf_split(w[(size_t)i*GATES + c], h, l);
    int p = c*HID + kswz(c, i);
    wh[p] = h; wl[p] = l;
}

__global__ void setup_comb(float* __restrict__ cwm, float* __restrict__ cb,
                           const float* __restrict__ fc1w, const float* __restrict__ fc1b,
                           const float* __restrict__ projw, const float* __restrict__ projb){
    int idx = blockIdx.x*256 + threadIdx.x;
    if (idx < 128*64) {
        int i = idx / 64, o = idx % 64;
        float v = 0.f;
        if (o < 35) {
            double s = 0.0;
            for (int m = 0; m < 128; m++) s += (double)fc1w[i*128+m] * (double)projw[m*35+o];
            v = (float)s;
        }
        cwm[idx] = v;
    } else if (idx < 128*64 + 64) {
        int o = idx - 128*64;
        float v = 0.f;
        if (o < 35) {
            double s = (double)projb[o];
            for (int m = 0; m < 128; m++) s += (double)fc1b[m] * (double)projw[m*35+o];
            v = (float)s;
        }
        cb[o] = v;
    }
}

// U (HID x GATES row-major) -> fp16 in MFMA B-fragment order for the
// 4-wave/8-fragment lstm_k: wave w (0..3) owns gate cols w*128..w*128+127.
__global__ void setup_uf(_Float16* __restrict__ uf, const float* __restrict__ u){
    int idx = blockIdx.x*256 + threadIdx.x;
    if (idx >= 65536) return;
    int j    = idx & 7;
    int lane = (idx >> 3) & 63;
    int nt   = (idx >> 9) & 7;
    int ks   = (idx >> 12) & 3;
    int w    = (idx >> 14) & 3;
    int k = ks*32 + (lane >> 4)*8 + j;
    int c = w*128 + nt*16 + (lane & 15);
    uf[idx] = (_Float16)u[(size_t)k*GATES + c];
}

// ---------------- MFMA split-bf16 GEMM ----------------
// Depth-2 software pipeline, single __syncthreads per K-step (R8 lesson:
// counted-vmcnt raw barriers are NULL-to-negative on this 2-phase structure;
// R7 form is the measured best).
//   WIDE=false: 128x128, 2x2 waves (N=128 ops: mel, conv)
//   WIDE=true:   64x256, 1x4 waves (N=512 ops: DFT, X-gemms)
//   PEPI=true: power epilogue (bin-interleaved DFT): store re^2+im^2 per bin.
enum AMode { A_NORMAL=0, A_FRAMES=1, A_CONV3=3 };

template<int AMODE, bool BIAS, int NT, bool WIDE, bool PEPI>
__global__ __launch_bounds__(256)
void mgemm_k(const float* __restrict__ A,
             const unsigned short* __restrict__ BTh, const unsigned short* __restrict__ BTl,
             const float* __restrict__ bias, float* __restrict__ C,
             int Ksteps, int lda, int kstride, int ldc,
             const float* __restrict__ aux, int rowbase)
{
    constexpr int BM = WIDE ? 64 : 128;
    constexpr int BN = WIDE ? 256 : 128;
    constexpr int AP = BM / 32;          // A staging passes (32 rows each)
    __shared__ unsigned short Ash[2][BM][32], Asl[2][BM][32];
    __shared__ unsigned short Bsh[2][BN][32], Bsl[2][BN][32];

    // bijective XCD-chunk swizzle (m204), n-tile fastest
    const int nwg = gridDim.x;
    const int qq = nwg >> 3, rmd = nwg & 7;
    const int xcd = blockIdx.x & 7, loc = blockIdx.x >> 3;
    const int swz = (xcd < rmd ? xcd*(qq+1) : rmd*(qq+1) + (xcd - rmd)*qq) + loc;
    constexpr int LGNT = (NT == 4) ? 2 : (NT == 2) ? 1 : 0;
    const int m0 = (swz >> LGNT) * BM;
    const int n0 = (swz & (NT-1)) * BN;

    const int tid = threadIdx.x;
    const int lane = tid & 63, w = tid >> 6;
    const int wr = WIDE ? 0 : (w >> 1) * 64;        // wave's 64x64 sub-tile
    const int wc = WIDE ? w * 64 : (w & 1) * 64;
    const int l15 = lane & 15;
    // swizzled chunk position for fragment reads: q ^ ((row>>1)&3)
    const int swf = ((lane & 15) >> 1) & 3;
    const int pos = (((lane >> 4) ^ swf) << 3);     // short index, 16B aligned

    // A staging: 8 threads/row, AP passes of 32 rows; thread covers 4 k-values
    const int sr  = tid >> 3;                       // row within pass
    const int wcol = (((((tid & 7) >> 1)) ^ ((tid >> 4) & 3)) << 3) + ((tid & 1) << 2);

    float va0[AP*4], va1[AP*4];

    auto issue_loads = [&](float (&va)[AP*4], int ksn){
        const int k0n = ksn * 32;
        #pragma unroll
        for (int p = 0; p < AP; p++) {
            const int row = p*32 + sr;
            const int kk = k0n + (tid & 7)*4;
            if constexpr (AMODE == A_NORMAL) {
                *(float4*)&va[p*4] = *(const float4*)(A + (size_t)(m0+row)*lda + kk);
            } else if constexpr (AMODE == A_FRAMES) {
                const int rr = rowbase + m0 + row;
                const int b = rr / NFRAME, f = rr - b*NFRAME;
                const float* xb = aux + (size_t)b * TLEN;
                const int q0 = f*HOP + kk - 200;
                if (q0 >= 0 && q0 + 3 < TLEN) {
                    *(float4*)&va[p*4] = *(const float4*)(xb + q0);
                } else {
                    #pragma unroll
                    for (int j = 0; j < 4; j++) {
                        int q = q0 + j;
                        if (q < 0) q = -q;
                        else if (q >= TLEN) q = 2*TLEN - 2 - q;
                        va[p*4+j] = xb[q];
                    }
                }
            } else { // A_CONV3
                const int rr = m0 + row;
                const int b = rr / TSTEPS, t = rr - b*TSTEPS;
                const int ksh = kk >> 7, i = kk & 127;
                *(float4*)&va[p*4] = *(const float4*)(aux + ((size_t)(b*NFRAME + t + ksh)*NMEL + i));
            }
        }
    };
    auto write_stage = [&](float (&va)[AP*4], int wb){
        #pragma unroll
        for (int p = 0; p < AP; p++) {
            const int row = p*32 + sr;
            us4 hv, lv;
            #pragma unroll
            for (int j = 0; j < 4; j++) {
                unsigned short h, l; bf_split_fast(va[p*4+j], h, l);
                hv[j] = h; lv[j] = l;
            }
            *(us4*)&Ash[wb][row][wcol] = hv;
            *(us4*)&Asl[wb][row][wcol] = lv;
        }
    };
    auto dma_b = [&](int wb, int ksn){
        const int k0n = ksn * 32;
        if constexpr (WIDE) {
            #pragma unroll
            for (int p = 0; p < 4; p++) {
                const int row = w*64 + p*16;
                const size_t o = (size_t)(n0 + row + (lane >> 2))*kstride + k0n + (lane & 3)*8;
                gld16(BTh + o, &Bsh[wb][row][0]);
                gld16(BTl + o, &Bsl[wb][row][0]);
            }
        } else {
            #pragma unroll
            for (int p = 0; p < 2; p++) {
                const int row = p*64 + w*16;
                const size_t o = (size_t)(n0 + row + (lane >> 2))*kstride + k0n + (lane & 3)*8;
                gld16(BTh + o, &Bsh[wb][row][0]);
                gld16(BTl + o, &Bsl[wb][row][0]);
            }
        }
    };

    f32x4 acc[4][4] = {};

    // prologue: stage ks=0 into buf0 (via set1 as temp), preload ks=1 into set0
    issue_loads(va1, 0);
    dma_b(0, 0);
    write_stage(va1, 0);
    issue_loads(va0, 1);
    __syncthreads();

    // iter body: cur regs hold data(ks+1); oth regs get data(ks+2); buf = ks&1
    auto iter = [&](int ks, float (&vac)[AP*4], float (&vao)[AP*4], int bufc){
        const bool pf1 = (ks + 1 < Ksteps);
        const bool pf2 = (ks + 2 < Ksteps);
        if (pf2) issue_loads(vao, ks + 2);
        if (pf1) dma_b(bufc ^ 1, ks + 1);

        bf16x8 ah[4], al[4];
        #pragma unroll
        for (int mt = 0; mt < 4; mt++) {
            ah[mt] = *(const bf16x8*)&Ash[bufc][wr + mt*16 + l15][pos];
            al[mt] = *(const bf16x8*)&Asl[bufc][wr + mt*16 + l15][pos];
        }
        #pragma unroll
        for (int nt = 0; nt < 4; nt++) {
            const int nr = wc + nt*16 + l15;
            bf16x8 bh = *(const bf16x8*)&Bsh[bufc][nr][pos];
            bf16x8 bl = *(const bf16x8*)&Bsl[bufc][nr][pos];
            #pragma unroll
            for (int mt = 0; mt < 4; mt++) {
                acc[mt][nt] = __builtin_amdgcn_mfma_f32_16x16x32_bf16(ah[mt], bh, acc[mt][nt], 0, 0, 0);
                acc[mt][nt] = __builtin_amdgcn_mfma_f32_16x16x32_bf16(ah[mt], bl, acc[mt][nt], 0, 0, 0);
                acc[mt][nt] = __builtin_amdgcn_mfma_f32_16x16x32_bf16(al[mt], bh, acc[mt][nt], 0, 0, 0);
            }
        }

        if (pf1) {
            write_stage(vac, bufc ^ 1);   // data(ks+1), loaded a full iter ago
            __syncthreads();
        }
    };

    for (int ks = 0; ks < Ksteps; ks += 2) {
        iter(ks, va0, va1, 0);
        if (ks + 1 < Ksteps) iter(ks + 1, va1, va0, 1);
    }

    const int quad = lane >> 4;
    if constexpr (PEPI) {
        // power epilogue: cols are bin-interleaved (2n=re, 2n+1=im). Each even
        // lane pairs with its odd neighbor via shfl_xor(1); store re^2+im^2.
        // Bins 201..223 (cols 402..447) are explicitly zeroed (mel pad).
        #pragma unroll
        for (int nt = 0; nt < 4; nt++) {
            const int col = n0 + wc + (nt << 4) + l15;
            #pragma unroll
            for (int mt = 0; mt < 4; mt++) {
                #pragma unroll
                for (int r = 0; r < 4; r++) {
                    const int row = m0 + wr + (mt << 4) + quad*4 + r;
                    const float v = acc[mt][nt][r];
                    const float u = __shfl_xor(v, 1);
                    if (!(l15 & 1)) {
                        if (col < 402)
                            C[(size_t)row*ldc + (col >> 1)] = v*v + u*u;
                        else if (col < 448)
                            C[(size_t)row*ldc + (col >> 1)] = 0.f;
                    }
                }
            }
        }
    } else {
        #pragma unroll
        for (int nt = 0; nt < 4; nt++) {
            const int col = n0 + wc + (nt << 4) + l15;
            float b = 0.f;
            if constexpr (BIAS) b = bias[col];
            #pragma unroll
            for (int mt = 0; mt < 4; mt++) {
                #pragma unroll
                for (int r = 0; r < 4; r++) {
                    const int row = m0 + wr + (mt << 4) + quad*4 + r;
                    C[(size_t)row*ldc + col] = acc[mt][nt][r] + b;
                }
            }
        }
    }
}

// ---------------- small fp32 GEMM (final 1024x35 only) ----------------
__global__ __launch_bounds__(256)
void gemm_small(const float* __restrict__ A, const float* __restrict__ Bm,
                const float* __restrict__ bias, float* __restrict__ C,
                int M, int N, int K, int lda, int ldb, int ldc)
{
    __shared__ float As[16][64+4];
    __shared__ float Bs[16][64];
    const int tid = threadIdx.x;
    const int tx = tid & 15, ty = tid >> 4;
    const int m0 = blockIdx.x * 64;
    float acc[4][4] = {{0,0,0,0},{0,0,0,0},{0,0,0,0},{0,0,0,0}};
    const int am = tid >> 2, ak = (tid & 3) * 4;
    const int bk = tid >> 4, bn = (tid & 15) * 4;
    for (int k0 = 0; k0 < K; k0 += 16) {
        float4 av = *(const float4*)(A + (size_t)(m0+am)*lda + k0 + ak);
        As[ak+0][am]=av.x; As[ak+1][am]=av.y; As[ak+2][am]=av.z; As[ak+3][am]=av.w;
        *(float4*)&Bs[bk][bn] = *(const float4*)(Bm + (size_t)(k0+bk)*ldb + bn);
        __syncthreads();
        #pragma unroll
        for (int k = 0; k < 16; k++) {
            float4 a = *(const float4*)&As[k][ty*4];
            float4 b = *(const float4*)&Bs[k][tx*4];
            #pragma unroll
            for (int i = 0; i < 4; i++) {
                float av_ = ((const float*)&a)[i];
                acc[i][0] = fmaf(av_, b.x, acc[i][0]);
                acc[i][1] = fmaf(av_, b.y, acc[i][1]);
                acc[i][2] = fmaf(av_, b.z, acc[i][2]);
                acc[i][3] = fmaf(av_, b.w, acc[i][3]);
            }
        }
        __syncthreads();
    }
    #pragma unroll
    for (int ir = 0; ir < 4; ir++) {
        const int row = m0 + ty*4 + ir;
        #pragma unroll
        for (int jc = 0; jc < 4; jc++) {
            const int col = tx*4 + jc;
            if (col < N) C[(size_t)row*ldc + col] = acc[ir][jc] + bias[col];
        }
    }
}

// ---------------- LSTM recurrence (exact R9 measured-best form) ----------------
__device__ __forceinline__ float sigm_f(float x){ return 1.f/(1.f + __expf(-x)); }
__device__ __forceinline__ float tanh_f(float x){ float e = __expf(2.f*x); return 1.f - 2.f/(e + 1.f); }

#define LROWS 2
#define LTHREADS 256
#define HPAD 136

__global__ __launch_bounds__(LTHREADS, 2)
void lstm_k(const float* __restrict__ X, const _Float16* __restrict__ Uf, float* __restrict__ H)
{
    __shared__ _Float16 hsA[16*HPAD];
    __shared__ float gs[GATES*5];
    const int tid = threadIdx.x;
    const int b0 = blockIdx.x * LROWS;
    const int lane = tid & 63, w = tid >> 6;      // w = 0..3
    const int m16 = lane & 15, quad = lane >> 4;
    const int r = tid >> 7;                       // 0..1
    const int j = tid & 127;

    // Preload B fragments, pin in VGPRs (R4/R5 lesson: plain loads get
    // rematerialized from L2 every step -> L2-bound).
    f32x4 bfr[4][8];
    #pragma unroll
    for (int ks = 0; ks < 4; ks++)
        #pragma unroll
        for (int nt = 0; nt < 8; nt++) {
            bfr[ks][nt] = *(const f32x4*)(Uf + ((((w*4 + ks)*8 + nt)*64 + lane) << 3));
            asm volatile("" : "+v"(bfr[ks][nt]));
        }

    for (int i = tid; i < 16*HPAD; i += LTHREADS) hsA[i] = (_Float16)0.f;
    float cst = 0.f;
    const float* xb = X + ((size_t)(b0 + r)*TSTEPS)*GATES + j;
    __syncthreads();

    // X prefetch: loaded one step early; LDS-only barriers below let these
    // loads stay in flight across both barriers.
    float xi = xb[0], xf = xb[128], xg = xb[256], xo = xb[384];

    for (int t = 0; t < TSTEPS; t++) {
        float xi_n = 0.f, xf_n = 0.f, xg_n = 0.f, xo_n = 0.f;
        if (t + 1 < TSTEPS) {
            const float* xp = xb + (size_t)(t + 1)*GATES;
            xi_n = xp[0]; xf_n = xp[128]; xg_n = xp[256]; xo_n = xp[384];
        }

        f16x8 ah[4];
        #pragma unroll
        for (int ks = 0; ks < 4; ks++)
            ah[ks] = *(const f16x8*)&hsA[m16*HPAD + ks*32 + quad*8];

        f32x4 acc[8] = {};
        #pragma unroll
        for (int ks = 0; ks < 4; ks++)
            #pragma unroll
            for (int nt = 0; nt < 8; nt++)
                acc[nt] = __builtin_amdgcn_mfma_f32_16x16x32_f16(
                    ah[ks], __builtin_bit_cast(f16x8, bfr[ks][nt]), acc[nt], 0, 0, 0);

        if (quad == 0) {
            #pragma unroll
            for (int nt = 0; nt < 8; nt++) {
                const int c = w*128 + nt*16 + m16;
                #pragma unroll
                for (int rr = 0; rr < LROWS; rr++) gs[c*5 + rr] = acc[nt][rr];
            }
        }
        barrier_lds();

        {
            const float gi = gs[(      j)*5 + r] + xi;
            const float gf = gs[(128 + j)*5 + r] + xf;
            const float gg = gs[(256 + j)*5 + r] + xg;
            const float go = gs[(384 + j)*5 + r] + xo;
            const float cn = sigm_f(gf)*cst + sigm_f(gi)*tanh_f(gg);
            cst = cn;
            const float hn = sigm_f(go)*tanh_f(cn);
            H[((size_t)(b0 + r)*TSTEPS + t)*HID + j] = hn;   // rides across barriers
            hsA[r*HPAD + j] = (_Float16)hn;
        }
        barrier_lds();

        xi = xi_n; xf = xf_n; xg = xg_n; xo = xo_n;
    }
}

// ---------------- mean over time ----------------
__global__ void mean_k(const float* __restrict__ H, float* __restrict__ Mh){
    const int idx = blockIdx.x*256 + threadIdx.x;
    if (idx >= BATCH*HID) return;
    const int b = idx >> 7, j = idx & 127;
    const float* p = H + (size_t)b*TSTEPS*HID + j;
    float s = 0.f;
    for (int t = 0; t < TSTEPS; t++) s += p[(size_t)t*HID];
    Mh[idx] = s * (1.0f/(float)TSTEPS);
}

// ---------------- launcher ----------------
extern "C" void kernel_launch(void* const* d_in, const int* in_sizes, int n_in,
                              void* d_out, int out_size, void* d_ws, size_t ws_size,
                              hipStream_t stream)
{
    const float* x      = (const float*)d_in[0];
    const float* conv_w = (const float*)d_in[1];
    const float* conv_b = (const float*)d_in[2];
    const float* W1     = (const float*)d_in[3];
    const float* U1     = (const float*)d_in[4];
    const float* b1     = (const float*)d_in[5];
    const float* W2     = (const float*)d_in[6];
    const float* U2     = (const float*)d_in[7];
    const float* b2     = (const float*)d_in[8];
    const float* fc1_w  = (const float*)d_in[9];
    const float* fc1_b  = (const float*)d_in[10];
    const float* proj_w = (const float*)d_in[11];
    const float* proj_b = (const float*)d_in[12];
    float* out = (float*)d_out;

    // ---- workspace layout (~241 MiB < 256 MiB) ----
    char* ws = (char*)d_ws;
    size_t off = 0;
    unsigned short* Tth = (unsigned short*)(ws + off); off = al512(off + (size_t)NDFT*KDFT*2);
    unsigned short* Ttl = (unsigned short*)(ws + off); off = al512(off + (size_t)NDFT*KDFT*2);
    unsigned short* fbh = (unsigned short*)(ws + off); off = al512(off + (size_t)NMEL*KPOW*2);
    unsigned short* fbl = (unsigned short*)(ws + off); off = al512(off + (size_t)NMEL*KPOW*2);
    unsigned short* wch = (unsigned short*)(ws + off); off = al512(off + (size_t)NMEL*KCONV*2);
    unsigned short* wcl = (unsigned short*)(ws + off); off = al512(off + (size_t)NMEL*KCONV*2);
    unsigned short* w1h = (unsigned short*)(ws + off); off = al512(off + (size_t)GATES*HID*2);
    unsigned short* w1l = (unsigned short*)(ws + off); off = al512(off + (size_t)GATES*HID*2);
    unsigned short* w2h = (unsigned short*)(ws + off); off = al512(off + (size_t)GATES*HID*2);
    unsigned short* w2l = (unsigned short*)(ws + off); off = al512(off + (size_t)GATES*HID*2);
    float* Cw   = (float*)(ws + off); off = al512(off + (size_t)128*64*4);
    float* Cb   = (float*)(ws + off); off = al512(off + (size_t)64*4);
    float* Mh   = (float*)(ws + off); off = al512(off + (size_t)BATCH*HID*4);
    _Float16* Uf1 = (_Float16*)(ws + off); off = al512(off + (size_t)65536*2);
    _Float16* Uf2 = (_Float16*)(ws + off); off = al512(off + (size_t)65536*2);
    float* MEL  = (float*)(ws + off); off = al512(off + (size_t)BATCH*NFRAME*NMEL*4);   // 42.5 MB
    float* CONV = (float*)(ws + off); off = al512(off + (size_t)BATCH*TSTEPS*NMEL*4);   // 41.4 MB
    float* X    = (float*)(ws + off); off = al512(off + (size_t)BATCH*TSTEPS*GATES*4);  // 165.7 MB
    float* POW = X;     // power scratch (TOTROWS*224*4 = 74.3 MB) dead before X written
    float* H1  = MEL;   // MEL dead after CONV computed
    float* H2  = CONV;  // CONV dead after X1 computed
    (void)ws_size; (void)out_size; (void)n_in; (void)in_sizes;

    // setup tables
    setup_dft_t<<<(NDFT*KDFT + 255)/256, 256, 0, stream>>>(Tth, Ttl);
    setup_fb_t <<<(NMEL*KPOW + 255)/256, 256, 0, stream>>>(fbh, fbl);
    setup_wc_t <<<(NMEL*KCONV + 255)/256, 256, 0, stream>>>(wch, wcl, conv_w);
    setup_w_t  <<<(GATES*HID + 255)/256, 256, 0, stream>>>(w1h, w1l, W1);
    setup_w_t  <<<(GATES*HID + 255)/256, 256, 0, stream>>>(w2h, w2l, W2);
    setup_comb <<<(128*64 + 64 + 255)/256, 256, 0, stream>>>(Cw, Cb, fc1_w, fc1_b, proj_w, proj_b);
    setup_uf   <<<65536/256, 256, 0, stream>>>(Uf1, U1);
    setup_uf   <<<65536/256, 256, 0, stream>>>(Uf2, U2);

    // mel spectrogram: frames @ interleaved-DFT (power fused in epilogue) -> POW @ fb
    mgemm_k<A_FRAMES,false,2,true,true><<<(TOTROWS/64)*2, 256, 0, stream>>>(
        nullptr, Tth, Ttl, nullptr, POW, KDFT/32, 0, KDFT, LPOW, x, 0);
    mgemm_k<A_NORMAL,false,1,false,false><<<TOTROWS/128, 256, 0, stream>>>(
        POW, fbh, fbl, nullptr, MEL, KPOW/32, LPOW, KPOW, NMEL, nullptr, 0);

    // conv1d (k=3, valid) as im2col GEMM, bias fused
    mgemm_k<A_CONV3,true,1,false,false><<<BATCH*TSTEPS/128, 256, 0, stream>>>(
        nullptr, wch, wcl, conv_b, CONV, KCONV/32, 0, KCONV, NMEL, MEL, 0);

    // layer 1: X1 = CONV @ W1 + b1 ; recurrence
    mgemm_k<A_NORMAL,true,2,true,false><<<(BATCH*TSTEPS/64)*2, 256, 0, stream>>>(
        CONV, w1h, w1l, b1, X, HID/32, NMEL, HID, GATES, nullptr, 0);
    lstm_k<<<BATCH/LROWS, LTHREADS, 0, stream>>>(X, Uf1, H1);

    // layer 2
    mgemm_k<A_NORMAL,true,2,true,false><<<(BATCH*TSTEPS/64)*2, 256, 0, stream>>>(
        H1, w2h, w2l, b2, X, HID/32, HID, HID, GATES, nullptr, 0);
    lstm_k<<<BATCH/LROWS, LTHREADS, 0, stream>>>(X, Uf2, H2);

    // mean over time, then folded fc1+proj
    mean_k<<<(BATCH*HID + 255)/256, 256, 0, stream>>>(H2, Mh);
    gemm_small<<<BATCH/64, 256, 0, stream>>>(Mh, Cw, Cb, out, BATCH, 35, HID, HID, 64, 35);
}